// Round 9
// baseline (244.844 us; speedup 1.0000x reference)
//
#include <hip/hip_runtime.h>
#include <math.h>

#define NN 8192
#define DD 128
#define THRESH 0.15f
#define NG (NN / 16)          // 512 candidate groups of 16
#define T0 0.147f             // absolute prefilter (bf16-safe: 0.15 - margin)
#define BWID 0.025f           // histogram bucket width
#define DELTA 0.004f          // 2x bf16 score error bound
#define CAPL 512              // per-row stored-candidate capacity (~395 expected)
#define CAP2 64               // per-row post-threshold survivor capacity (~10 expected)
#define KSEL 5u               // cumulative count incl. self (=4 excl.) -> top-4 safe

typedef __attribute__((ext_vector_type(8))) short short8;
typedef __attribute__((ext_vector_type(4))) float f32x4;
typedef __attribute__((ext_vector_type(4))) unsigned int u32x4;
typedef unsigned long long u64;

__device__ __forceinline__ unsigned short f2bf(float f) {
    unsigned int u = __float_as_uint(f);
    return (unsigned short)((u + 0x7fffu + ((u >> 16) & 1u)) >> 16);
}

__device__ __forceinline__ u64 shfl_xor_u64(u64 v, int d) {
    unsigned lo = (unsigned)v, hi = (unsigned)(v >> 32);
    lo = __shfl_xor(lo, d); hi = __shfl_xor(hi, d);
    return ((u64)hi << 32) | lo;
}

// sorted-desc top-4 insert (tie: smaller index). Only on wave-uniform data.
__device__ __forceinline__ void ins4(float v, int j, float* tv, int* ti) {
    bool b3 = (v > tv[3]) | ((v == tv[3]) & (j < ti[3]));
    if (b3) {
        bool b0 = (v > tv[0]) | ((v == tv[0]) & (j < ti[0]));
        bool b1 = (v > tv[1]) | ((v == tv[1]) & (j < ti[1]));
        bool b2 = (v > tv[2]) | ((v == tv[2]) & (j < ti[2]));
        if (b0)      { tv[3]=tv[2];ti[3]=ti[2]; tv[2]=tv[1];ti[2]=ti[1]; tv[1]=tv[0];ti[1]=ti[0]; tv[0]=v;ti[0]=j; }
        else if (b1) { tv[3]=tv[2];ti[3]=ti[2]; tv[2]=tv[1];ti[2]=ti[1]; tv[1]=v;ti[1]=j; }
        else if (b2) { tv[3]=tv[2];ti[3]=ti[2]; tv[2]=v;ti[2]=j; }
        else         { tv[3]=v;ti[3]=j; }
    }
}

// ---- K-fill: plain cached grid-stride zero of both outputs ----
__global__ __launch_bounds__(256) void fill_zero(f32x4* __restrict__ o) {
    const f32x4 z = {0.f, 0.f, 0.f, 0.f};
    const size_t total = (size_t)NN * NN / 2;
    const size_t stride = (size_t)2048 * 256;
    size_t idx = (size_t)blockIdx.x * 256 + threadIdx.x;
#pragma unroll 4
    for (; idx < total; idx += stride) o[idx] = z;
}

// ---- K1: normalize rows, emit bf16 x-hat in MFMA-fragment-major layout ----
__global__ __launch_bounds__(256) void norm_frag(const float* __restrict__ x,
                                                 u32x4* __restrict__ F) {
    const int t = threadIdx.x;
    const int c = blockIdx.x;
    const int row = t >> 4;
    const int seg = t & 15;
    const float* xr = x + (size_t)(c * 16 + row) * DD + seg * 8;
    float4 v0 = reinterpret_cast<const float4*>(xr)[0];
    float4 v1 = reinterpret_cast<const float4*>(xr)[1];
    float ss = v0.x*v0.x + v0.y*v0.y + v0.z*v0.z + v0.w*v0.w
             + v1.x*v1.x + v1.y*v1.y + v1.z*v1.z + v1.w*v1.w;
#pragma unroll
    for (int d = 1; d < 16; d <<= 1) ss += __shfl_xor(ss, d);
    const float inv = 1.0f / fmaxf(sqrtf(ss), 1e-12f);
    u32x4 p;
    p.x = ((unsigned)f2bf(v0.y*inv) << 16) | f2bf(v0.x*inv);
    p.y = ((unsigned)f2bf(v0.w*inv) << 16) | f2bf(v0.z*inv);
    p.z = ((unsigned)f2bf(v1.y*inv) << 16) | f2bf(v1.x*inv);
    p.w = ((unsigned)f2bf(v1.w*inv) << 16) | f2bf(v1.z*inv);
    const int kc = seg >> 2, r = seg & 3;
    F[(size_t)(c * 4 + kc) * 64 + r * 16 + row] = p;
}

// ---- K2: single sweep (histogram + store-all>T0) + threshold + rerank ----
__global__ __launch_bounds__(512) void build(const short8* __restrict__ F,
                                             const float* __restrict__ x,
                                             float* __restrict__ adj,
                                             float* __restrict__ ew) {
    __shared__ unsigned list[32][CAPL];                     // 64 KB packed (val|idx)
    __shared__ u64 hsA_lo[16][8], hsA_hi[16][8], hsB_lo[16][8], hsB_hi[16][8];
    __shared__ float rowthr[32];
    __shared__ unsigned cnt[32], cnt2[32];
    __shared__ int li2[32][CAP2];                           // 8 KB survivors

    const int t = threadIdx.x, lane = t & 63, w = t >> 6;   // 8 waves
    const int i0 = blockIdx.x * 32;
    const int l15 = lane & 15, r = lane >> 4;
    const int g0 = i0 >> 4;

    if (t < 32) { cnt[t] = 0u; cnt2[t] = 0u; }

    short8 rf0[4], rf1[4];
#pragma unroll
    for (int kc = 0; kc < 4; ++kc) {
        rf0[kc] = F[(size_t)(g0 * 4 + kc) * 64 + lane];
        rf1[kc] = F[(size_t)((g0 + 1) * 4 + kc) * 64 + lane];
    }
    __syncthreads();          // cnt init visible before appends

    u64 hA = 0ull, hB = 0ull; // 8 x 8-bit packed bucket counters per row-half

    // ---- single sweep: histogram + append all values > T0 (diag included) ----
    for (int cg = w; cg < NG; cg += 8) {
        const short8 a0 = F[(size_t)(cg * 4 + 0) * 64 + lane];
        const short8 a1 = F[(size_t)(cg * 4 + 1) * 64 + lane];
        const short8 a2 = F[(size_t)(cg * 4 + 2) * 64 + lane];
        const short8 a3 = F[(size_t)(cg * 4 + 3) * 64 + lane];
        f32x4 acc0 = {0.f, 0.f, 0.f, 0.f}, acc1 = {0.f, 0.f, 0.f, 0.f};
        acc0 = __builtin_amdgcn_mfma_f32_16x16x32_bf16(a0, rf0[0], acc0, 0, 0, 0);
        acc1 = __builtin_amdgcn_mfma_f32_16x16x32_bf16(a0, rf1[0], acc1, 0, 0, 0);
        acc0 = __builtin_amdgcn_mfma_f32_16x16x32_bf16(a1, rf0[1], acc0, 0, 0, 0);
        acc1 = __builtin_amdgcn_mfma_f32_16x16x32_bf16(a1, rf1[1], acc1, 0, 0, 0);
        acc0 = __builtin_amdgcn_mfma_f32_16x16x32_bf16(a2, rf0[2], acc0, 0, 0, 0);
        acc1 = __builtin_amdgcn_mfma_f32_16x16x32_bf16(a2, rf1[2], acc1, 0, 0, 0);
        acc0 = __builtin_amdgcn_mfma_f32_16x16x32_bf16(a3, rf0[3], acc0, 0, 0, 0);
        acc1 = __builtin_amdgcn_mfma_f32_16x16x32_bf16(a3, rf1[3], acc1, 0, 0, 0);
        const int jb = cg * 16 + r * 4;
#pragma unroll
        for (int q = 0; q < 4; ++q) {
            const unsigned j = (unsigned)(jb + q);
            {
                const float v = acc0[q];
                if (v > T0) {
                    int b = (int)((v - T0) * 40.0f); b = b > 7 ? 7 : b;
                    hA += 1ull << (b * 8);
                    unsigned p = atomicAdd(&cnt[l15], 1u);
                    if (p < CAPL)
                        list[l15][p] = (__float_as_uint(v) & 0xFFFFE000u) | j;
                }
            }
            {
                const float v = acc1[q];
                if (v > T0) {
                    int b = (int)((v - T0) * 40.0f); b = b > 7 ? 7 : b;
                    hB += 1ull << (b * 8);
                    unsigned p = atomicAdd(&cnt[l15 + 16], 1u);
                    if (p < CAPL)
                        list[l15 + 16][p] = (__float_as_uint(v) & 0xFFFFE000u) | j;
                }
            }
        }
    }

    // merge the 4 r-lanes per row (byte headroom: 4 x ~30 << 255)
    hA += shfl_xor_u64(hA, 16); hA += shfl_xor_u64(hA, 32);
    hB += shfl_xor_u64(hB, 16); hB += shfl_xor_u64(hB, 32);
    if (r == 0) {
        const u64 M = 0x00FF00FF00FF00FFull;
        hsA_lo[l15][w] = hA & M;  hsA_hi[l15][w] = (hA >> 8) & M;
        hsB_lo[l15][w] = hB & M;  hsB_hi[l15][w] = (hB >> 8) & M;
    }
    __syncthreads();

    // ---- per-row threshold: highest bucket with cumulative (incl self) >= KSEL ----
    if (t < 32) {
        const int row = t & 15;
        u64 lo = 0ull, hi = 0ull;
        if (t < 16) {
#pragma unroll
            for (int ww = 0; ww < 8; ++ww) { lo += hsA_lo[row][ww]; hi += hsA_hi[row][ww]; }
        } else {
#pragma unroll
            for (int ww = 0; ww < 8; ++ww) { lo += hsB_lo[row][ww]; hi += hsB_hi[row][ww]; }
        }
        unsigned cum = 0; int pick = 0;
#pragma unroll
        for (int b = 7; b >= 0; --b) {
            unsigned c = (unsigned)(((b & 1) ? hi : lo) >> (16 * (b >> 1))) & 0xFFFFu;
            cum += c;
            if (cum >= KSEL) { pick = b; break; }
        }
        rowthr[t] = T0 + BWID * (float)pick - DELTA;
    }
    __syncthreads();

    // ---- compaction: filter stored list down to survivors > rowthr ----
#pragma unroll
    for (int rr = 0; rr < 4; ++rr) {
        const int lrow = w * 4 + rr;
        const int i = i0 + lrow;
        const int n = min((int)cnt[lrow], CAPL);
        const float thr = rowthr[lrow];
        for (int e = lane; e < n; e += 64) {
            const unsigned pk = list[lrow][e];
            const float va = __uint_as_float(pk & 0xFFFFE000u);
            const int j = (int)(pk & 0x1FFFu);
            if (va > thr && j != i) {
                unsigned p = atomicAdd(&cnt2[lrow], 1u);
                if (p < CAP2) li2[lrow][p] = j;
            }
        }
    }
    __syncthreads();

    // ---- exact fp32 rerank + scatter: wave w handles rows w*4 .. w*4+3 ----
    for (int rr = 0; rr < 4; ++rr) {
        const int lrow = w * 4 + rr;
        const int i = i0 + lrow;
        const int n = min((int)cnt2[lrow], CAP2);
        const float2 a = reinterpret_cast<const float2*>(x + (size_t)i * DD)[lane];
        float ss = a.x * a.x + a.y * a.y;
#pragma unroll
        for (int d = 1; d < 64; d <<= 1) ss += __shfl_xor(ss, d);
        const float ni = fmaxf(sqrtf(ss), 1e-12f);
        float tv[4]; int ti[4];
#pragma unroll
        for (int s = 0; s < 4; ++s) { tv[s] = -1e30f; ti[s] = 0x7fffffff; }
        for (int c = 0; c < n; ++c) {
            const int j = li2[lrow][c];
            const float2 b = reinterpret_cast<const float2*>(x + (size_t)j * DD)[lane];
            float dp = a.x * b.x + a.y * b.y;
            float sb = b.x * b.x + b.y * b.y;
#pragma unroll
            for (int d = 1; d < 64; d <<= 1) {
                dp += __shfl_xor(dp, d);
                sb += __shfl_xor(sb, d);
            }
            const float sim = dp / (ni * fmaxf(sqrtf(sb), 1e-12f));
            ins4(sim, j, tv, ti);
        }
        if (lane == 0) {
#pragma unroll
            for (int s = 0; s < 4; ++s)
                if (tv[s] > THRESH) {
                    adj[(size_t)i * NN + ti[s]] = 1.0f;
                    ew [(size_t)i * NN + ti[s]] = tv[s];
                }
        }
    }
}

extern "C" void kernel_launch(void* const* d_in, const int* in_sizes, int n_in,
                              void* d_out, int out_size, void* d_ws, size_t ws_size,
                              hipStream_t stream) {
    const float* x = (const float*)d_in[0];
    u32x4* F = (u32x4*)d_ws;                               // 2 MB fragment-major x-hat
    float* adj = (float*)d_out;
    float* ew  = adj + (size_t)NN * NN;

    hipLaunchKernelGGL(fill_zero, dim3(2048),  dim3(256), 0, stream, (f32x4*)d_out);
    hipLaunchKernelGGL(norm_frag, dim3(NG),    dim3(256), 0, stream, x, F);
    hipLaunchKernelGGL(build,     dim3(NN/32), dim3(512), 0, stream,
                       (const short8*)F, x, adj, ew);
}

// Round 10
// 218.276 us; speedup vs baseline: 1.1217x; 1.1217x over previous
//
#include <hip/hip_runtime.h>
#include <math.h>

#define NN 8192
#define DD 128
#define THRESH 0.15f
#define NG 512            // candidate groups of 16

typedef __attribute__((ext_vector_type(8))) short short8;
typedef __attribute__((ext_vector_type(4))) float f32x4;
typedef __attribute__((ext_vector_type(4))) unsigned int u32x4;

__device__ __forceinline__ unsigned umax2(unsigned a, unsigned b) { return a > b ? a : b; }
__device__ __forceinline__ unsigned umin2(unsigned a, unsigned b) { return a < b ? a : b; }
#define CEX(A, B) { unsigned _h = umax2(A, B); B = umin2(A, B); A = _h; }

__device__ __forceinline__ unsigned short f2bf(float f) {
    unsigned int u = __float_as_uint(f);
    return (unsigned short)((u + 0x7fffu + ((u >> 16) & 1u)) >> 16);
}

// branch-free insert of key k into sorted-desc m[0..7]
__device__ __forceinline__ void ins8k(unsigned* m, unsigned k) {
#pragma unroll
    for (int s = 0; s < 8; ++s) { unsigned h = umax2(m[s], k); k = umin2(m[s], k); m[s] = h; }
}

// merge my sorted-8 with lane^d's sorted-8, keep top-8 (bitonic)
__device__ __forceinline__ void merge8(unsigned* m, int d) {
    unsigned z[8];
#pragma unroll
    for (int s = 0; s < 8; ++s) z[s] = umax2(m[s], __shfl_xor(m[7 - s], d));
    CEX(z[0],z[4]); CEX(z[1],z[5]); CEX(z[2],z[6]); CEX(z[3],z[7]);
    CEX(z[0],z[2]); CEX(z[1],z[3]); CEX(z[4],z[6]); CEX(z[5],z[7]);
    CEX(z[0],z[1]); CEX(z[2],z[3]); CEX(z[4],z[5]); CEX(z[6],z[7]);
#pragma unroll
    for (int s = 0; s < 8; ++s) m[s] = z[s];
}

// merge my sorted-16 with lane^d's sorted-16, keep top-16 (bitonic)
__device__ __forceinline__ void merge16(unsigned* K, int d) {
    unsigned z[16];
#pragma unroll
    for (int s = 0; s < 16; ++s) z[s] = umax2(K[s], __shfl_xor(K[15 - s], d));
#pragma unroll
    for (int s = 0; s < 8; ++s) CEX(z[s], z[s + 8]);
    CEX(z[0],z[4]);  CEX(z[1],z[5]);  CEX(z[2],z[6]);  CEX(z[3],z[7]);
    CEX(z[8],z[12]); CEX(z[9],z[13]); CEX(z[10],z[14]); CEX(z[11],z[15]);
    CEX(z[0],z[2]);  CEX(z[1],z[3]);  CEX(z[4],z[6]);  CEX(z[5],z[7]);
    CEX(z[8],z[10]); CEX(z[9],z[11]); CEX(z[12],z[14]); CEX(z[13],z[15]);
#pragma unroll
    for (int s = 0; s < 16; s += 2) CEX(z[s], z[s + 1]);
#pragma unroll
    for (int s = 0; s < 16; ++s) K[s] = z[s];
}

// sorted-desc top-4 insert (tie: smaller index). Only on wave-uniform data.
__device__ __forceinline__ void ins4(float v, int j, float* tv, int* ti) {
    bool b3 = (v > tv[3]) | ((v == tv[3]) & (j < ti[3]));
    if (b3) {
        bool b0 = (v > tv[0]) | ((v == tv[0]) & (j < ti[0]));
        bool b1 = (v > tv[1]) | ((v == tv[1]) & (j < ti[1]));
        bool b2 = (v > tv[2]) | ((v == tv[2]) & (j < ti[2]));
        if (b0)      { tv[3]=tv[2];ti[3]=ti[2]; tv[2]=tv[1];ti[2]=ti[1]; tv[1]=tv[0];ti[1]=ti[0]; tv[0]=v;ti[0]=j; }
        else if (b1) { tv[3]=tv[2];ti[3]=ti[2]; tv[2]=tv[1];ti[2]=ti[1]; tv[1]=v;ti[1]=j; }
        else if (b2) { tv[3]=tv[2];ti[3]=ti[2]; tv[2]=v;ti[2]=j; }
        else         { tv[3]=v;ti[3]=j; }
    }
}

// ---- K-fill: plain cached grid-stride zero of both outputs ----
__global__ __launch_bounds__(256) void fill_zero(f32x4* __restrict__ o) {
    const f32x4 z = {0.f, 0.f, 0.f, 0.f};
    const size_t total = (size_t)NN * NN / 2;
    const size_t stride = (size_t)2048 * 256;
    size_t idx = (size_t)blockIdx.x * 256 + threadIdx.x;
#pragma unroll 4
    for (; idx < total; idx += stride) o[idx] = z;
}

// ---- K1: normalize rows, emit bf16 x-hat in MFMA-fragment-major layout ----
__global__ __launch_bounds__(256) void norm_frag(const float* __restrict__ x,
                                                 u32x4* __restrict__ F) {
    const int t = threadIdx.x;
    const int c = blockIdx.x;
    const int row = t >> 4;
    const int seg = t & 15;
    const float* xr = x + (size_t)(c * 16 + row) * DD + seg * 8;
    float4 v0 = reinterpret_cast<const float4*>(xr)[0];
    float4 v1 = reinterpret_cast<const float4*>(xr)[1];
    float ss = v0.x*v0.x + v0.y*v0.y + v0.z*v0.z + v0.w*v0.w
             + v1.x*v1.x + v1.y*v1.y + v1.z*v1.z + v1.w*v1.w;
#pragma unroll
    for (int d = 1; d < 16; d <<= 1) ss += __shfl_xor(ss, d);
    const float inv = 1.0f / fmaxf(sqrtf(ss), 1e-12f);
    u32x4 p;
    p.x = ((unsigned)f2bf(v0.y*inv) << 16) | f2bf(v0.x*inv);
    p.y = ((unsigned)f2bf(v0.w*inv) << 16) | f2bf(v0.z*inv);
    p.z = ((unsigned)f2bf(v1.y*inv) << 16) | f2bf(v1.x*inv);
    p.w = ((unsigned)f2bf(v1.w*inv) << 16) | f2bf(v1.z*inv);
    const int kc = seg >> 2, r = seg & 3;
    F[(size_t)(c * 4 + kc) * 64 + r * 16 + row] = p;
}

// ---- K2: one sweep, branch-free per-lane top-8 keys; bitonic merges to
// row top-16; exact fp32 rerank of <=16; scatter. 1024 thr (16 waves). ----
__global__ __launch_bounds__(1024, 4) void build(const short8* __restrict__ F,
                                                 const float* __restrict__ x,
                                                 float* __restrict__ adj,
                                                 float* __restrict__ ew) {
    __shared__ unsigned wvk[16][32][8];                    // 16 KB
    const int t = threadIdx.x, lane = t & 63, w = t >> 6;  // 16 waves
    const int i0 = blockIdx.x * 32;
    const int l15 = lane & 15, r = lane >> 4;
    const int g0 = i0 >> 4;

    short8 rf0[4], rf1[4];
#pragma unroll
    for (int kc = 0; kc < 4; ++kc) {
        rf0[kc] = F[(size_t)(g0 * 4 + kc) * 64 + lane];
        rf1[kc] = F[(size_t)((g0 + 1) * 4 + kc) * 64 + lane];
    }

    unsigned m0[8], m1[8];
#pragma unroll
    for (int s = 0; s < 8; ++s) { m0[s] = 0u; m1[s] = 0u; }

    // ---- sweep: wave w covers cg in {w, w+16, ...}, 32 iters ----
    for (int it = 0; it < 32; ++it) {
        const int cg = (it << 4) | w;
        const short8 a0 = F[(size_t)(cg * 4 + 0) * 64 + lane];
        const short8 a1 = F[(size_t)(cg * 4 + 1) * 64 + lane];
        const short8 a2 = F[(size_t)(cg * 4 + 2) * 64 + lane];
        const short8 a3 = F[(size_t)(cg * 4 + 3) * 64 + lane];
        f32x4 acc0 = {0.f, 0.f, 0.f, 0.f}, acc1 = {0.f, 0.f, 0.f, 0.f};
        acc0 = __builtin_amdgcn_mfma_f32_16x16x32_bf16(a0, rf0[0], acc0, 0, 0, 0);
        acc1 = __builtin_amdgcn_mfma_f32_16x16x32_bf16(a0, rf1[0], acc1, 0, 0, 0);
        acc0 = __builtin_amdgcn_mfma_f32_16x16x32_bf16(a1, rf0[1], acc0, 0, 0, 0);
        acc1 = __builtin_amdgcn_mfma_f32_16x16x32_bf16(a1, rf1[1], acc1, 0, 0, 0);
        acc0 = __builtin_amdgcn_mfma_f32_16x16x32_bf16(a2, rf0[2], acc0, 0, 0, 0);
        acc1 = __builtin_amdgcn_mfma_f32_16x16x32_bf16(a2, rf1[2], acc1, 0, 0, 0);
        acc0 = __builtin_amdgcn_mfma_f32_16x16x32_bf16(a3, rf0[3], acc0, 0, 0, 0);
        acc1 = __builtin_amdgcn_mfma_f32_16x16x32_bf16(a3, rf1[3], acc1, 0, 0, 0);
        const unsigned jb = (unsigned)(cg * 16 + r * 4);
#pragma unroll
        for (int q = 0; q < 4; ++q) {
            const unsigned k0 =
                (__float_as_uint(fmaxf(acc0[q], 0.f)) & 0xFFFFE000u) | (jb + q);
            ins8k(m0, k0);
            const unsigned k1 =
                (__float_as_uint(fmaxf(acc1[q], 0.f)) & 0xFFFFE000u) | (jb + q);
            ins8k(m1, k1);
        }
    }

    // merge the 4 r-lanes sharing each row -> per-wave row top-8
    merge8(m0, 16); merge8(m0, 32);
    merge8(m1, 16); merge8(m1, 32);
    if (r == 0) {
#pragma unroll
        for (int s = 0; s < 8; ++s) {
            wvk[w][l15][s]      = m0[s];
            wvk[w][l15 + 16][s] = m1[s];
        }
    }
    __syncthreads();

    // ---- final: wave w handles rows 2w, 2w+1 ----
    for (int rr = 0; rr < 2; ++rr) {
        const int lrow = w * 2 + rr;
        const int i = i0 + lrow;
        // 128 keys (16 waves x 8) -> 2 per lane -> butterfly to row top-16
        const unsigned e0 = wvk[lane >> 3][lrow][lane & 7];
        const unsigned e1 = wvk[8 + (lane >> 3)][lrow][lane & 7];
        unsigned K[16];
        K[0] = umax2(e0, e1); K[1] = umin2(e0, e1);
#pragma unroll
        for (int s = 2; s < 16; ++s) K[s] = 0u;
        merge16(K, 1); merge16(K, 2); merge16(K, 4);
        merge16(K, 8); merge16(K, 16); merge16(K, 32);

        // exact fp32 rerank of the <=16 kept candidates
        const float2 av = reinterpret_cast<const float2*>(x + (size_t)i * DD)[lane];
        float ss = av.x * av.x + av.y * av.y;
#pragma unroll
        for (int d = 1; d < 64; d <<= 1) ss += __shfl_xor(ss, d);
        const float ni = fmaxf(sqrtf(ss), 1e-12f);
        float tv[4]; int ti[4];
#pragma unroll
        for (int s = 0; s < 4; ++s) { tv[s] = -1e30f; ti[s] = 0x7fffffff; }
#pragma unroll
        for (int c = 0; c < 16; ++c) {
            const unsigned key = K[c];
            const int j = (int)(key & 0x1FFFu);
            if (key == 0u || j == i) continue;          // wave-uniform branches
            const float2 bv = reinterpret_cast<const float2*>(x + (size_t)j * DD)[lane];
            float dp = av.x * bv.x + av.y * bv.y;
            float sb = bv.x * bv.x + bv.y * bv.y;
#pragma unroll
            for (int d = 1; d < 64; d <<= 1) {
                dp += __shfl_xor(dp, d);
                sb += __shfl_xor(sb, d);
            }
            const float sim = dp / (ni * fmaxf(sqrtf(sb), 1e-12f));
            ins4(sim, j, tv, ti);
        }
        if (lane == 0) {
#pragma unroll
            for (int s = 0; s < 4; ++s)
                if (tv[s] > THRESH) {
                    adj[(size_t)i * NN + ti[s]] = 1.0f;
                    ew [(size_t)i * NN + ti[s]] = tv[s];
                }
        }
    }
}

extern "C" void kernel_launch(void* const* d_in, const int* in_sizes, int n_in,
                              void* d_out, int out_size, void* d_ws, size_t ws_size,
                              hipStream_t stream) {
    const float* x = (const float*)d_in[0];
    u32x4* F = (u32x4*)d_ws;                               // 2 MB fragment-major x-hat
    float* adj = (float*)d_out;
    float* ew  = adj + (size_t)NN * NN;

    hipLaunchKernelGGL(fill_zero, dim3(2048),  dim3(256),  0, stream, (f32x4*)d_out);
    hipLaunchKernelGGL(norm_frag, dim3(NG),    dim3(256),  0, stream, x, F);
    hipLaunchKernelGGL(build,     dim3(NN/32), dim3(1024), 0, stream,
                       (const short8*)F, x, adj, ew);
}

// Round 11
// 182.232 us; speedup vs baseline: 1.3436x; 1.1978x over previous
//
#include <hip/hip_runtime.h>
#include <math.h>

#define NN 8192
#define DD 128
#define THRESH 0.15f
#define NCOMP 256         // compute blocks (32 rows each), dispatched first
#define NFILL 1280        // fill blocks

typedef __attribute__((ext_vector_type(8))) short short8;
typedef __attribute__((ext_vector_type(4))) float f32x4;
typedef __attribute__((ext_vector_type(4))) unsigned int u32x4;

__device__ __forceinline__ unsigned umax2(unsigned a, unsigned b) { return a > b ? a : b; }
__device__ __forceinline__ unsigned umin2(unsigned a, unsigned b) { return a < b ? a : b; }
#define CEX(A, B) { unsigned _h = umax2(A, B); B = umin2(A, B); A = _h; }

__device__ __forceinline__ unsigned short f2bf(float f) {
    unsigned int u = __float_as_uint(f);
    return (unsigned short)((u + 0x7fffu + ((u >> 16) & 1u)) >> 16);
}

// branch-free insert of key k into sorted-desc m[0..7]
__device__ __forceinline__ void ins8k(unsigned* m, unsigned k) {
#pragma unroll
    for (int s = 0; s < 8; ++s) { unsigned h = umax2(m[s], k); k = umin2(m[s], k); m[s] = h; }
}

// merge my sorted-8 with lane^d's sorted-8, keep top-8 (bitonic)
__device__ __forceinline__ void merge8(unsigned* m, int d) {
    unsigned z[8];
#pragma unroll
    for (int s = 0; s < 8; ++s) z[s] = umax2(m[s], __shfl_xor(m[7 - s], d));
    CEX(z[0],z[4]); CEX(z[1],z[5]); CEX(z[2],z[6]); CEX(z[3],z[7]);
    CEX(z[0],z[2]); CEX(z[1],z[3]); CEX(z[4],z[6]); CEX(z[5],z[7]);
    CEX(z[0],z[1]); CEX(z[2],z[3]); CEX(z[4],z[5]); CEX(z[6],z[7]);
#pragma unroll
    for (int s = 0; s < 8; ++s) m[s] = z[s];
}

// merge my sorted-16 with lane^d's sorted-16, keep top-16 (bitonic)
__device__ __forceinline__ void merge16(unsigned* K, int d) {
    unsigned z[16];
#pragma unroll
    for (int s = 0; s < 16; ++s) z[s] = umax2(K[s], __shfl_xor(K[15 - s], d));
#pragma unroll
    for (int s = 0; s < 8; ++s) CEX(z[s], z[s + 8]);
    CEX(z[0],z[4]);  CEX(z[1],z[5]);  CEX(z[2],z[6]);  CEX(z[3],z[7]);
    CEX(z[8],z[12]); CEX(z[9],z[13]); CEX(z[10],z[14]); CEX(z[11],z[15]);
    CEX(z[0],z[2]);  CEX(z[1],z[3]);  CEX(z[4],z[6]);  CEX(z[5],z[7]);
    CEX(z[8],z[10]); CEX(z[9],z[11]); CEX(z[12],z[14]); CEX(z[13],z[15]);
#pragma unroll
    for (int s = 0; s < 16; s += 2) CEX(z[s], z[s + 1]);
#pragma unroll
    for (int s = 0; s < 16; ++s) K[s] = z[s];
}

// sorted-desc top-4 insert (tie: smaller index). Only on wave-uniform data.
__device__ __forceinline__ void ins4(float v, int j, float* tv, int* ti) {
    bool b3 = (v > tv[3]) | ((v == tv[3]) & (j < ti[3]));
    if (b3) {
        bool b0 = (v > tv[0]) | ((v == tv[0]) & (j < ti[0]));
        bool b1 = (v > tv[1]) | ((v == tv[1]) & (j < ti[1]));
        bool b2 = (v > tv[2]) | ((v == tv[2]) & (j < ti[2]));
        if (b0)      { tv[3]=tv[2];ti[3]=ti[2]; tv[2]=tv[1];ti[2]=ti[1]; tv[1]=tv[0];ti[1]=ti[0]; tv[0]=v;ti[0]=j; }
        else if (b1) { tv[3]=tv[2];ti[3]=ti[2]; tv[2]=tv[1];ti[2]=ti[1]; tv[1]=v;ti[1]=j; }
        else if (b2) { tv[3]=tv[2];ti[3]=ti[2]; tv[2]=v;ti[2]=j; }
        else         { tv[3]=v;ti[3]=j; }
    }
}

// ---- K1: normalize rows, emit bf16 x-hat in MFMA-fragment-major layout ----
__global__ __launch_bounds__(256) void norm_frag(const float* __restrict__ x,
                                                 u32x4* __restrict__ F) {
    const int t = threadIdx.x;
    const int c = blockIdx.x;
    const int row = t >> 4;
    const int seg = t & 15;
    const float* xr = x + (size_t)(c * 16 + row) * DD + seg * 8;
    float4 v0 = reinterpret_cast<const float4*>(xr)[0];
    float4 v1 = reinterpret_cast<const float4*>(xr)[1];
    float ss = v0.x*v0.x + v0.y*v0.y + v0.z*v0.z + v0.w*v0.w
             + v1.x*v1.x + v1.y*v1.y + v1.z*v1.z + v1.w*v1.w;
#pragma unroll
    for (int d = 1; d < 16; d <<= 1) ss += __shfl_xor(ss, d);
    const float inv = 1.0f / fmaxf(sqrtf(ss), 1e-12f);
    u32x4 p;
    p.x = ((unsigned)f2bf(v0.y*inv) << 16) | f2bf(v0.x*inv);
    p.y = ((unsigned)f2bf(v0.w*inv) << 16) | f2bf(v0.z*inv);
    p.z = ((unsigned)f2bf(v1.y*inv) << 16) | f2bf(v1.x*inv);
    p.w = ((unsigned)f2bf(v1.w*inv) << 16) | f2bf(v1.z*inv);
    const int kc = seg >> 2, r = seg & 3;
    F[(size_t)(c * 4 + kc) * 64 + r * 16 + row] = p;
}

// ---- K2: fused role-split. Blocks 0..255: MFMA sweep + branch-free top-k,
// emit per-row top-16 keys to ws. Blocks 256..1535: zero-fill both outputs. ----
__global__ __launch_bounds__(512, 4) void fused_fill_build(const short8* __restrict__ F,
                                                           unsigned* __restrict__ keys,
                                                           float* __restrict__ out) {
    const int bid = blockIdx.x;
    const int t = threadIdx.x;

    if (bid >= NCOMP) {
        // ---- fill role: grid-stride plain float4 stores over both outputs ----
        const int fid = bid - NCOMP;
        f32x4* o = reinterpret_cast<f32x4*>(out);
        const f32x4 z = {0.f, 0.f, 0.f, 0.f};
        const size_t total = (size_t)NN * NN / 2;
        const size_t stride = (size_t)NFILL * 512;
#pragma unroll 4
        for (size_t idx = (size_t)fid * 512 + t; idx < total; idx += stride)
            o[idx] = z;
        return;
    }

    // ---- compute role: 32 rows, 8 waves, full 8192-candidate sweep ----
    __shared__ unsigned wvk[8][32][8];                     // 8 KB
    const int lane = t & 63, w = t >> 6;
    const int i0 = bid * 32;
    const int l15 = lane & 15, r = lane >> 4;
    const int g0 = i0 >> 4;

    short8 rf0[4], rf1[4];
#pragma unroll
    for (int kc = 0; kc < 4; ++kc) {
        rf0[kc] = F[(size_t)(g0 * 4 + kc) * 64 + lane];
        rf1[kc] = F[(size_t)((g0 + 1) * 4 + kc) * 64 + lane];
    }

    unsigned m0[8], m1[8];
#pragma unroll
    for (int s = 0; s < 8; ++s) { m0[s] = 0u; m1[s] = 0u; }

    for (int it = 0; it < 64; ++it) {
        const int cg = (it << 3) | w;
        const short8 a0 = F[(size_t)(cg * 4 + 0) * 64 + lane];
        const short8 a1 = F[(size_t)(cg * 4 + 1) * 64 + lane];
        const short8 a2 = F[(size_t)(cg * 4 + 2) * 64 + lane];
        const short8 a3 = F[(size_t)(cg * 4 + 3) * 64 + lane];
        f32x4 acc0 = {0.f, 0.f, 0.f, 0.f}, acc1 = {0.f, 0.f, 0.f, 0.f};
        acc0 = __builtin_amdgcn_mfma_f32_16x16x32_bf16(a0, rf0[0], acc0, 0, 0, 0);
        acc1 = __builtin_amdgcn_mfma_f32_16x16x32_bf16(a0, rf1[0], acc1, 0, 0, 0);
        acc0 = __builtin_amdgcn_mfma_f32_16x16x32_bf16(a1, rf0[1], acc0, 0, 0, 0);
        acc1 = __builtin_amdgcn_mfma_f32_16x16x32_bf16(a1, rf1[1], acc1, 0, 0, 0);
        acc0 = __builtin_amdgcn_mfma_f32_16x16x32_bf16(a2, rf0[2], acc0, 0, 0, 0);
        acc1 = __builtin_amdgcn_mfma_f32_16x16x32_bf16(a2, rf1[2], acc1, 0, 0, 0);
        acc0 = __builtin_amdgcn_mfma_f32_16x16x32_bf16(a3, rf0[3], acc0, 0, 0, 0);
        acc1 = __builtin_amdgcn_mfma_f32_16x16x32_bf16(a3, rf1[3], acc1, 0, 0, 0);
        const unsigned jb = (unsigned)(cg * 16 + r * 4);
#pragma unroll
        for (int q = 0; q < 4; ++q) {
            const unsigned k0 =
                (__float_as_uint(fmaxf(acc0[q], 0.f)) & 0xFFFFE000u) | (jb + q);
            ins8k(m0, k0);
            const unsigned k1 =
                (__float_as_uint(fmaxf(acc1[q], 0.f)) & 0xFFFFE000u) | (jb + q);
            ins8k(m1, k1);
        }
    }

    // merge the 4 r-lanes sharing each row -> per-wave row top-8
    merge8(m0, 16); merge8(m0, 32);
    merge8(m1, 16); merge8(m1, 32);
    if (r == 0) {
#pragma unroll
        for (int s = 0; s < 8; ++s) {
            wvk[w][l15][s]      = m0[s];
            wvk[w][l15 + 16][s] = m1[s];
        }
    }
    __syncthreads();

    // ---- final: wave w merges rows 4w..4w+3 to top-16, writes keys ----
    for (int rr = 0; rr < 4; ++rr) {
        const int lrow = w * 4 + rr;
        // 64 keys (8 waves x 8) -> 1 per lane -> butterfly to row top-16
        const unsigned e0 = wvk[lane >> 3][lrow][lane & 7];
        unsigned K[16];
        K[0] = e0;
#pragma unroll
        for (int s = 1; s < 16; ++s) K[s] = 0u;
        merge16(K, 1); merge16(K, 2); merge16(K, 4);
        merge16(K, 8); merge16(K, 16); merge16(K, 32);
        if (lane == 0) {
#pragma unroll
            for (int s = 0; s < 16; ++s)
                keys[(size_t)(i0 + lrow) * 16 + s] = K[s];
        }
    }
}

// ---- K3: exact fp32 rerank of each row's 16 keys, scatter adj/ew ----
__global__ __launch_bounds__(256) void rerank(const float* __restrict__ x,
                                              const unsigned* __restrict__ keys,
                                              float* __restrict__ adj,
                                              float* __restrict__ ew) {
    const int t = threadIdx.x, lane = t & 63, w = t >> 6;
    const int i = blockIdx.x * 4 + w;
    const float2 a = reinterpret_cast<const float2*>(x + (size_t)i * DD)[lane];
    float ss = a.x * a.x + a.y * a.y;
#pragma unroll
    for (int d = 1; d < 64; d <<= 1) ss += __shfl_xor(ss, d);
    const float ni = fmaxf(sqrtf(ss), 1e-12f);
    float tv[4]; int ti[4];
#pragma unroll
    for (int s = 0; s < 4; ++s) { tv[s] = -1e30f; ti[s] = 0x7fffffff; }
#pragma unroll
    for (int c = 0; c < 16; ++c) {
        const unsigned key = keys[(size_t)i * 16 + c];
        const int j = (int)(key & 0x1FFFu);
        if (key == 0u || j == i) continue;               // wave-uniform branch
        const float2 b = reinterpret_cast<const float2*>(x + (size_t)j * DD)[lane];
        float dp = a.x * b.x + a.y * b.y;
        float sb = b.x * b.x + b.y * b.y;
#pragma unroll
        for (int d = 1; d < 64; d <<= 1) {
            dp += __shfl_xor(dp, d);
            sb += __shfl_xor(sb, d);
        }
        const float sim = dp / (ni * fmaxf(sqrtf(sb), 1e-12f));
        ins4(sim, j, tv, ti);
    }
    if (lane == 0) {
#pragma unroll
        for (int s = 0; s < 4; ++s)
            if (tv[s] > THRESH) {
                adj[(size_t)i * NN + ti[s]] = 1.0f;
                ew [(size_t)i * NN + ti[s]] = tv[s];
            }
    }
}

extern "C" void kernel_launch(void* const* d_in, const int* in_sizes, int n_in,
                              void* d_out, int out_size, void* d_ws, size_t ws_size,
                              hipStream_t stream) {
    const float* x = (const float*)d_in[0];
    u32x4* F = (u32x4*)d_ws;                               // 2 MB fragment-major x-hat
    unsigned* keys = (unsigned*)((char*)d_ws + (2u << 20)); // 512 KB top-16 keys
    float* adj = (float*)d_out;
    float* ew  = adj + (size_t)NN * NN;

    hipLaunchKernelGGL(norm_frag, dim3(NN / 16), dim3(256), 0, stream, x, F);
    hipLaunchKernelGGL(fused_fill_build, dim3(NCOMP + NFILL), dim3(512), 0, stream,
                       (const short8*)F, keys, (float*)d_out);
    hipLaunchKernelGGL(rerank, dim3(NN / 4), dim3(256), 0, stream, x, keys, adj, ew);
}

// Round 12
// 149.192 us; speedup vs baseline: 1.6411x; 1.2215x over previous
//
#include <hip/hip_runtime.h>
#include <math.h>

#define NN 8192
#define DD 128
#define THRESH 0.15f

typedef __attribute__((ext_vector_type(8))) short short8;
typedef __attribute__((ext_vector_type(4))) float f32x4;
typedef __attribute__((ext_vector_type(4))) unsigned int u32x4;

__device__ __forceinline__ unsigned umax2(unsigned a, unsigned b) { return a > b ? a : b; }
__device__ __forceinline__ unsigned umin2(unsigned a, unsigned b) { return a < b ? a : b; }
#define CEX(A, B) { unsigned _h = umax2(A, B); B = umin2(A, B); A = _h; }

__device__ __forceinline__ unsigned short f2bf(float f) {
    unsigned int u = __float_as_uint(f);
    return (unsigned short)((u + 0x7fffu + ((u >> 16) & 1u)) >> 16);
}

// branch-free insert of key k into sorted-desc m[0..7]
__device__ __forceinline__ void ins8k(unsigned* m, unsigned k) {
#pragma unroll
    for (int s = 0; s < 8; ++s) { unsigned h = umax2(m[s], k); k = umin2(m[s], k); m[s] = h; }
}

// merge my sorted-8 with lane^d's sorted-8, keep top-8 (bitonic)
__device__ __forceinline__ void merge8(unsigned* m, int d) {
    unsigned z[8];
#pragma unroll
    for (int s = 0; s < 8; ++s) z[s] = umax2(m[s], __shfl_xor(m[7 - s], d));
    CEX(z[0],z[4]); CEX(z[1],z[5]); CEX(z[2],z[6]); CEX(z[3],z[7]);
    CEX(z[0],z[2]); CEX(z[1],z[3]); CEX(z[4],z[6]); CEX(z[5],z[7]);
    CEX(z[0],z[1]); CEX(z[2],z[3]); CEX(z[4],z[5]); CEX(z[6],z[7]);
#pragma unroll
    for (int s = 0; s < 8; ++s) m[s] = z[s];
}

// merge my sorted-16 with lane^d's sorted-16, keep top-16 (bitonic)
__device__ __forceinline__ void merge16(unsigned* K, int d) {
    unsigned z[16];
#pragma unroll
    for (int s = 0; s < 16; ++s) z[s] = umax2(K[s], __shfl_xor(K[15 - s], d));
#pragma unroll
    for (int s = 0; s < 8; ++s) CEX(z[s], z[s + 8]);
    CEX(z[0],z[4]);  CEX(z[1],z[5]);  CEX(z[2],z[6]);  CEX(z[3],z[7]);
    CEX(z[8],z[12]); CEX(z[9],z[13]); CEX(z[10],z[14]); CEX(z[11],z[15]);
    CEX(z[0],z[2]);  CEX(z[1],z[3]);  CEX(z[4],z[6]);  CEX(z[5],z[7]);
    CEX(z[8],z[10]); CEX(z[9],z[11]); CEX(z[12],z[14]); CEX(z[13],z[15]);
#pragma unroll
    for (int s = 0; s < 16; s += 2) CEX(z[s], z[s + 1]);
#pragma unroll
    for (int s = 0; s < 16; ++s) K[s] = z[s];
}

// sorted-desc top-4 insert (tie: smaller index). Only on wave-uniform data.
__device__ __forceinline__ void ins4(float v, int j, float* tv, int* ti) {
    bool b3 = (v > tv[3]) | ((v == tv[3]) & (j < ti[3]));
    if (b3) {
        bool b0 = (v > tv[0]) | ((v == tv[0]) & (j < ti[0]));
        bool b1 = (v > tv[1]) | ((v == tv[1]) & (j < ti[1]));
        bool b2 = (v > tv[2]) | ((v == tv[2]) & (j < ti[2]));
        if (b0)      { tv[3]=tv[2];ti[3]=ti[2]; tv[2]=tv[1];ti[2]=ti[1]; tv[1]=tv[0];ti[1]=ti[0]; tv[0]=v;ti[0]=j; }
        else if (b1) { tv[3]=tv[2];ti[3]=ti[2]; tv[2]=tv[1];ti[2]=ti[1]; tv[1]=v;ti[1]=j; }
        else if (b2) { tv[3]=tv[2];ti[3]=ti[2]; tv[2]=v;ti[2]=j; }
        else         { tv[3]=v;ti[3]=j; }
    }
}

// ---- K1: normalize rows, emit bf16 x-hat in MFMA-fragment-major layout ----
__global__ __launch_bounds__(256) void norm_frag(const float* __restrict__ x,
                                                 u32x4* __restrict__ F) {
    const int t = threadIdx.x;
    const int c = blockIdx.x;
    const int row = t >> 4;
    const int seg = t & 15;
    const float* xr = x + (size_t)(c * 16 + row) * DD + seg * 8;
    float4 v0 = reinterpret_cast<const float4*>(xr)[0];
    float4 v1 = reinterpret_cast<const float4*>(xr)[1];
    float ss = v0.x*v0.x + v0.y*v0.y + v0.z*v0.z + v0.w*v0.w
             + v1.x*v1.x + v1.y*v1.y + v1.z*v1.z + v1.w*v1.w;
#pragma unroll
    for (int d = 1; d < 16; d <<= 1) ss += __shfl_xor(ss, d);
    const float inv = 1.0f / fmaxf(sqrtf(ss), 1e-12f);
    u32x4 p;
    p.x = ((unsigned)f2bf(v0.y*inv) << 16) | f2bf(v0.x*inv);
    p.y = ((unsigned)f2bf(v0.w*inv) << 16) | f2bf(v0.z*inv);
    p.z = ((unsigned)f2bf(v1.y*inv) << 16) | f2bf(v1.x*inv);
    p.w = ((unsigned)f2bf(v1.w*inv) << 16) | f2bf(v1.z*inv);
    const int kc = seg >> 2, r = seg & 3;
    F[(size_t)(c * 4 + kc) * 64 + r * 16 + row] = p;
}

// ---- K2: homogeneous fused sweep. 512 blocks x 512 thr, 2 blocks/CU.
// Each block: 16 rows, full 8192-cand MFMA sweep w/ branch-free top-8 keys,
// PLUS its contiguous 1 MiB share of the output zero-fill, interleaved. ----
__global__ __launch_bounds__(512, 4) void fused_build(const short8* __restrict__ F,
                                                      unsigned* __restrict__ keys,
                                                      f32x4* __restrict__ out) {
    __shared__ unsigned wvk[8][16][8];                     // 4 KB
    const int bid = blockIdx.x;
    const int t = threadIdx.x, lane = t & 63, w = t >> 6;  // 8 waves
    const int i0 = bid * 16;
    const int l15 = lane & 15, r = lane >> 4;

    short8 rf[4];
#pragma unroll
    for (int kc = 0; kc < 4; ++kc)
        rf[kc] = F[(size_t)(bid * 4 + kc) * 64 + lane];

    unsigned m0[8];
#pragma unroll
    for (int s = 0; s < 8; ++s) m0[s] = 0u;

    const f32x4 z = {0.f, 0.f, 0.f, 0.f};
    const size_t fb = (size_t)bid * 65536 + t;             // block's f32x4 fill base

    for (int it = 0; it < 64; ++it) {
        const int cg = (it << 3) | w;
        const short8 a0 = F[(size_t)(cg * 4 + 0) * 64 + lane];
        const short8 a1 = F[(size_t)(cg * 4 + 1) * 64 + lane];
        const short8 a2 = F[(size_t)(cg * 4 + 2) * 64 + lane];
        const short8 a3 = F[(size_t)(cg * 4 + 3) * 64 + lane];
        f32x4 acc = {0.f, 0.f, 0.f, 0.f};
        acc = __builtin_amdgcn_mfma_f32_16x16x32_bf16(a0, rf[0], acc, 0, 0, 0);
        acc = __builtin_amdgcn_mfma_f32_16x16x32_bf16(a1, rf[1], acc, 0, 0, 0);
        acc = __builtin_amdgcn_mfma_f32_16x16x32_bf16(a2, rf[2], acc, 0, 0, 0);
        acc = __builtin_amdgcn_mfma_f32_16x16x32_bf16(a3, rf[3], acc, 0, 0, 0);

        // interleaved zero-fill: 2 coalesced f32x4 stores (fire-and-forget)
        out[fb + it * 1024]       = z;
        out[fb + it * 1024 + 512] = z;

        const unsigned jb = (unsigned)(cg * 16 + r * 4);
#pragma unroll
        for (int q = 0; q < 4; ++q) {
            const unsigned k0 =
                (__float_as_uint(fmaxf(acc[q], 0.f)) & 0xFFFFE000u) | (jb + q);
            ins8k(m0, k0);
        }
    }

    // merge the 4 r-lanes sharing each row -> per-wave row top-8
    merge8(m0, 16); merge8(m0, 32);
    if (r == 0) {
#pragma unroll
        for (int s = 0; s < 8; ++s) wvk[w][l15][s] = m0[s];
    }
    __syncthreads();

    // ---- final: wave w merges rows 2w, 2w+1 -> top-16, writes keys ----
    for (int rr = 0; rr < 2; ++rr) {
        const int lrow = w * 2 + rr;
        const unsigned e0 = wvk[lane >> 3][lrow][lane & 7];   // 64 keys, 1/lane
        unsigned K[16];
        K[0] = e0;
#pragma unroll
        for (int s = 1; s < 16; ++s) K[s] = 0u;
        merge16(K, 1); merge16(K, 2); merge16(K, 4);
        merge16(K, 8); merge16(K, 16); merge16(K, 32);
        if (lane == 0) {
#pragma unroll
            for (int s = 0; s < 16; ++s)
                keys[(size_t)(i0 + lrow) * 16 + s] = K[s];
        }
    }
}

// ---- K3: exact fp32 rerank of each row's 16 keys, scatter adj/ew ----
__global__ __launch_bounds__(256) void rerank(const float* __restrict__ x,
                                              const unsigned* __restrict__ keys,
                                              float* __restrict__ adj,
                                              float* __restrict__ ew) {
    const int t = threadIdx.x, lane = t & 63, w = t >> 6;
    const int i = blockIdx.x * 4 + w;
    const float2 a = reinterpret_cast<const float2*>(x + (size_t)i * DD)[lane];
    float ss = a.x * a.x + a.y * a.y;
#pragma unroll
    for (int d = 1; d < 64; d <<= 1) ss += __shfl_xor(ss, d);
    const float ni = fmaxf(sqrtf(ss), 1e-12f);
    float tv[4]; int ti[4];
#pragma unroll
    for (int s = 0; s < 4; ++s) { tv[s] = -1e30f; ti[s] = 0x7fffffff; }
#pragma unroll
    for (int c = 0; c < 16; ++c) {
        const unsigned key = keys[(size_t)i * 16 + c];
        const int j = (int)(key & 0x1FFFu);
        if (key == 0u || j == i) continue;               // wave-uniform branch
        const float2 b = reinterpret_cast<const float2*>(x + (size_t)j * DD)[lane];
        float dp = a.x * b.x + a.y * b.y;
        float sb = b.x * b.x + b.y * b.y;
#pragma unroll
        for (int d = 1; d < 64; d <<= 1) {
            dp += __shfl_xor(dp, d);
            sb += __shfl_xor(sb, d);
        }
        const float sim = dp / (ni * fmaxf(sqrtf(sb), 1e-12f));
        ins4(sim, j, tv, ti);
    }
    if (lane == 0) {
#pragma unroll
        for (int s = 0; s < 4; ++s)
            if (tv[s] > THRESH) {
                adj[(size_t)i * NN + ti[s]] = 1.0f;
                ew [(size_t)i * NN + ti[s]] = tv[s];
            }
    }
}

extern "C" void kernel_launch(void* const* d_in, const int* in_sizes, int n_in,
                              void* d_out, int out_size, void* d_ws, size_t ws_size,
                              hipStream_t stream) {
    const float* x = (const float*)d_in[0];
    u32x4* F = (u32x4*)d_ws;                                // 2 MB fragment-major x-hat
    unsigned* keys = (unsigned*)((char*)d_ws + (2u << 20)); // 512 KB top-16 keys
    float* adj = (float*)d_out;
    float* ew  = adj + (size_t)NN * NN;

    hipLaunchKernelGGL(norm_frag,   dim3(NN / 16), dim3(256), 0, stream, x, F);
    hipLaunchKernelGGL(fused_build, dim3(512),     dim3(512), 0, stream,
                       (const short8*)F, keys, (f32x4*)d_out);
    hipLaunchKernelGGL(rerank,      dim3(NN / 4),  dim3(256), 0, stream, x, keys, adj, ew);
}

// Round 14
// 147.398 us; speedup vs baseline: 1.6611x; 1.0122x over previous
//
#include <hip/hip_runtime.h>
#include <math.h>

#define NN 8192
#define DD 128
#define THRESH 0.15f

typedef __attribute__((ext_vector_type(8))) short short8;
typedef __attribute__((ext_vector_type(4))) float f32x4;
typedef __attribute__((ext_vector_type(4))) unsigned int u32x4;

__device__ __forceinline__ unsigned umax2(unsigned a, unsigned b) { return a > b ? a : b; }
__device__ __forceinline__ unsigned umin2(unsigned a, unsigned b) { return a < b ? a : b; }
#define CEX(A, B) { unsigned _h = umax2(A, B); B = umin2(A, B); A = _h; }

__device__ __forceinline__ unsigned short f2bf(float f) {
    unsigned int u = __float_as_uint(f);
    return (unsigned short)((u + 0x7fffu + ((u >> 16) & 1u)) >> 16);
}

// branch-free insert of key k into sorted-desc m[0..7]
__device__ __forceinline__ void ins8k(unsigned* m, unsigned k) {
#pragma unroll
    for (int s = 0; s < 8; ++s) { unsigned h = umax2(m[s], k); k = umin2(m[s], k); m[s] = h; }
}

// in-lane merge: A <- top-8 of (A union B), both sorted desc
__device__ __forceinline__ void mergeTop8(unsigned* A, const unsigned* B) {
    unsigned z[8];
#pragma unroll
    for (int s = 0; s < 8; ++s) z[s] = umax2(A[s], B[7 - s]);
    CEX(z[0],z[4]); CEX(z[1],z[5]); CEX(z[2],z[6]); CEX(z[3],z[7]);
    CEX(z[0],z[2]); CEX(z[1],z[3]); CEX(z[4],z[6]); CEX(z[5],z[7]);
    CEX(z[0],z[1]); CEX(z[2],z[3]); CEX(z[4],z[5]); CEX(z[6],z[7]);
#pragma unroll
    for (int s = 0; s < 8; ++s) A[s] = z[s];
}

// merge my sorted-8 with lane^d's sorted-8, keep top-8 (bitonic)
__device__ __forceinline__ void merge8(unsigned* m, int d) {
    unsigned z[8];
#pragma unroll
    for (int s = 0; s < 8; ++s) z[s] = umax2(m[s], __shfl_xor(m[7 - s], d));
    CEX(z[0],z[4]); CEX(z[1],z[5]); CEX(z[2],z[6]); CEX(z[3],z[7]);
    CEX(z[0],z[2]); CEX(z[1],z[3]); CEX(z[4],z[6]); CEX(z[5],z[7]);
    CEX(z[0],z[1]); CEX(z[2],z[3]); CEX(z[4],z[5]); CEX(z[6],z[7]);
#pragma unroll
    for (int s = 0; s < 8; ++s) m[s] = z[s];
}

// merge my sorted-16 with lane^d's sorted-16, keep top-16 (bitonic)
__device__ __forceinline__ void merge16(unsigned* K, int d) {
    unsigned z[16];
#pragma unroll
    for (int s = 0; s < 16; ++s) z[s] = umax2(K[s], __shfl_xor(K[15 - s], d));
#pragma unroll
    for (int s = 0; s < 8; ++s) CEX(z[s], z[s + 8]);
    CEX(z[0],z[4]);  CEX(z[1],z[5]);  CEX(z[2],z[6]);  CEX(z[3],z[7]);
    CEX(z[8],z[12]); CEX(z[9],z[13]); CEX(z[10],z[14]); CEX(z[11],z[15]);
    CEX(z[0],z[2]);  CEX(z[1],z[3]);  CEX(z[4],z[6]);  CEX(z[5],z[7]);
    CEX(z[8],z[10]); CEX(z[9],z[11]); CEX(z[12],z[14]); CEX(z[13],z[15]);
#pragma unroll
    for (int s = 0; s < 16; s += 2) CEX(z[s], z[s + 1]);
#pragma unroll
    for (int s = 0; s < 16; ++s) K[s] = z[s];
}

// sorted-desc top-4 insert (tie: smaller index). Only on wave-uniform data.
__device__ __forceinline__ void ins4(float v, int j, float* tv, int* ti) {
    bool b3 = (v > tv[3]) | ((v == tv[3]) & (j < ti[3]));
    if (b3) {
        bool b0 = (v > tv[0]) | ((v == tv[0]) & (j < ti[0]));
        bool b1 = (v > tv[1]) | ((v == tv[1]) & (j < ti[1]));
        bool b2 = (v > tv[2]) | ((v == tv[2]) & (j < ti[2]));
        if (b0)      { tv[3]=tv[2];ti[3]=ti[2]; tv[2]=tv[1];ti[2]=ti[1]; tv[1]=tv[0];ti[1]=ti[0]; tv[0]=v;ti[0]=j; }
        else if (b1) { tv[3]=tv[2];ti[3]=ti[2]; tv[2]=tv[1];ti[2]=ti[1]; tv[1]=v;ti[1]=j; }
        else if (b2) { tv[3]=tv[2];ti[3]=ti[2]; tv[2]=v;ti[2]=j; }
        else         { tv[3]=v;ti[3]=j; }
    }
}

// ---- K1: normalize rows, emit bf16 x-hat in MFMA-fragment-major layout ----
__global__ __launch_bounds__(256) void norm_frag(const float* __restrict__ x,
                                                 u32x4* __restrict__ F) {
    const int t = threadIdx.x;
    const int c = blockIdx.x;
    const int row = t >> 4;
    const int seg = t & 15;
    const float* xr = x + (size_t)(c * 16 + row) * DD + seg * 8;
    float4 v0 = reinterpret_cast<const float4*>(xr)[0];
    float4 v1 = reinterpret_cast<const float4*>(xr)[1];
    float ss = v0.x*v0.x + v0.y*v0.y + v0.z*v0.z + v0.w*v0.w
             + v1.x*v1.x + v1.y*v1.y + v1.z*v1.z + v1.w*v1.w;
#pragma unroll
    for (int d = 1; d < 16; d <<= 1) ss += __shfl_xor(ss, d);
    const float inv = 1.0f / fmaxf(sqrtf(ss), 1e-12f);
    u32x4 p;
    p.x = ((unsigned)f2bf(v0.y*inv) << 16) | f2bf(v0.x*inv);
    p.y = ((unsigned)f2bf(v0.w*inv) << 16) | f2bf(v0.z*inv);
    p.z = ((unsigned)f2bf(v1.y*inv) << 16) | f2bf(v1.x*inv);
    p.w = ((unsigned)f2bf(v1.w*inv) << 16) | f2bf(v1.z*inv);
    const int kc = seg >> 2, r = seg & 3;
    F[(size_t)(c * 4 + kc) * 64 + r * 16 + row] = p;
}

// ---- K2: homogeneous fused sweep, 4 independent per-lane top-8 lists
// (breaks the ins8k loop-carried dependency chain), interleaved zero-fill. ----
__global__ __launch_bounds__(512, 4) void fused_build(const short8* __restrict__ F,
                                                      unsigned* __restrict__ keys,
                                                      f32x4* __restrict__ out) {
    __shared__ unsigned wvk[8][16][8];                     // 4 KB
    const int bid = blockIdx.x;
    const int t = threadIdx.x, lane = t & 63, w = t >> 6;  // 8 waves
    const int i0 = bid * 16;
    const int l15 = lane & 15, r = lane >> 4;

    short8 rf[4];
#pragma unroll
    for (int kc = 0; kc < 4; ++kc)
        rf[kc] = F[(size_t)(bid * 4 + kc) * 64 + lane];

    unsigned mA[8], mB[8], mC[8], mD[8];
#pragma unroll
    for (int s = 0; s < 8; ++s) { mA[s] = 0u; mB[s] = 0u; mC[s] = 0u; mD[s] = 0u; }

    const f32x4 z = {0.f, 0.f, 0.f, 0.f};
    const size_t fb = (size_t)bid * 65536 + t;             // block's f32x4 fill base

    for (int it = 0; it < 64; ++it) {
        const int cg = (it << 3) | w;
        const short8 a0 = F[(size_t)(cg * 4 + 0) * 64 + lane];
        const short8 a1 = F[(size_t)(cg * 4 + 1) * 64 + lane];
        const short8 a2 = F[(size_t)(cg * 4 + 2) * 64 + lane];
        const short8 a3 = F[(size_t)(cg * 4 + 3) * 64 + lane];
        f32x4 acc = {0.f, 0.f, 0.f, 0.f};
        acc = __builtin_amdgcn_mfma_f32_16x16x32_bf16(a0, rf[0], acc, 0, 0, 0);
        acc = __builtin_amdgcn_mfma_f32_16x16x32_bf16(a1, rf[1], acc, 0, 0, 0);
        acc = __builtin_amdgcn_mfma_f32_16x16x32_bf16(a2, rf[2], acc, 0, 0, 0);
        acc = __builtin_amdgcn_mfma_f32_16x16x32_bf16(a3, rf[3], acc, 0, 0, 0);

        // interleaved zero-fill: 2 coalesced f32x4 stores (fire-and-forget)
        out[fb + it * 1024]       = z;
        out[fb + it * 1024 + 512] = z;

        const unsigned jb = (unsigned)(cg * 16 + r * 4);
        // 4 parallel insert chains (one list per q) — no intra-iter serialization
        ins8k(mA, (__float_as_uint(fmaxf(acc[0], 0.f)) & 0xFFFFE000u) | (jb + 0));
        ins8k(mB, (__float_as_uint(fmaxf(acc[1], 0.f)) & 0xFFFFE000u) | (jb + 1));
        ins8k(mC, (__float_as_uint(fmaxf(acc[2], 0.f)) & 0xFFFFE000u) | (jb + 2));
        ins8k(mD, (__float_as_uint(fmaxf(acc[3], 0.f)) & 0xFFFFE000u) | (jb + 3));
    }

    // fold the 4 streams into one sorted-8 (union top-8 superset of lane top-8)
    mergeTop8(mA, mB);
    mergeTop8(mC, mD);
    mergeTop8(mA, mC);

    // merge the 4 r-lanes sharing each row -> per-wave row top-8
    merge8(mA, 16); merge8(mA, 32);
    if (r == 0) {
#pragma unroll
        for (int s = 0; s < 8; ++s) wvk[w][l15][s] = mA[s];
    }
    __syncthreads();

    // ---- final: wave w merges rows 2w, 2w+1 -> top-16, writes keys ----
    for (int rr = 0; rr < 2; ++rr) {
        const int lrow = w * 2 + rr;
        const unsigned e0 = wvk[lane >> 3][lrow][lane & 7];   // 64 keys, 1/lane
        unsigned K[16];
        K[0] = e0;
#pragma unroll
        for (int s = 1; s < 16; ++s) K[s] = 0u;
        merge16(K, 1); merge16(K, 2); merge16(K, 4);
        merge16(K, 8); merge16(K, 16); merge16(K, 32);
        if (lane == 0) {
#pragma unroll
            for (int s = 0; s < 16; ++s)
                keys[(size_t)(i0 + lrow) * 16 + s] = K[s];
        }
    }
}

// ---- K3: exact fp32 rerank of each row's 16 keys, scatter adj/ew ----
__global__ __launch_bounds__(256) void rerank(const float* __restrict__ x,
                                              const unsigned* __restrict__ keys,
                                              float* __restrict__ adj,
                                              float* __restrict__ ew) {
    const int t = threadIdx.x, lane = t & 63, w = t >> 6;
    const int i = blockIdx.x * 4 + w;
    const float2 a = reinterpret_cast<const float2*>(x + (size_t)i * DD)[lane];
    float ss = a.x * a.x + a.y * a.y;
#pragma unroll
    for (int d = 1; d < 64; d <<= 1) ss += __shfl_xor(ss, d);
    const float ni = fmaxf(sqrtf(ss), 1e-12f);
    float tv[4]; int ti[4];
#pragma unroll
    for (int s = 0; s < 4; ++s) { tv[s] = -1e30f; ti[s] = 0x7fffffff; }
#pragma unroll
    for (int c = 0; c < 16; ++c) {
        const unsigned key = keys[(size_t)i * 16 + c];
        const int j = (int)(key & 0x1FFFu);
        if (key == 0u || j == i) continue;               // wave-uniform branch
        const float2 b = reinterpret_cast<const float2*>(x + (size_t)j * DD)[lane];
        float dp = a.x * b.x + a.y * b.y;
        float sb = b.x * b.x + b.y * b.y;
#pragma unroll
        for (int d = 1; d < 64; d <<= 1) {
            dp += __shfl_xor(dp, d);
            sb += __shfl_xor(sb, d);
        }
        const float sim = dp / (ni * fmaxf(sqrtf(sb), 1e-12f));
        ins4(sim, j, tv, ti);
    }
    if (lane == 0) {
#pragma unroll
        for (int s = 0; s < 4; ++s)
            if (tv[s] > THRESH) {
                adj[(size_t)i * NN + ti[s]] = 1.0f;
                ew [(size_t)i * NN + ti[s]] = tv[s];
            }
    }
}

extern "C" void kernel_launch(void* const* d_in, const int* in_sizes, int n_in,
                              void* d_out, int out_size, void* d_ws, size_t ws_size,
                              hipStream_t stream) {
    const float* x = (const float*)d_in[0];
    u32x4* F = (u32x4*)d_ws;                                // 2 MB fragment-major x-hat
    unsigned* keys = (unsigned*)((char*)d_ws + (2u << 20)); // 512 KB top-16 keys
    float* adj = (float*)d_out;
    float* ew  = adj + (size_t)NN * NN;

    hipLaunchKernelGGL(norm_frag,   dim3(NN / 16), dim3(256), 0, stream, x, F);
    hipLaunchKernelGGL(fused_build, dim3(512),     dim3(512), 0, stream,
                       (const short8*)F, keys, (f32x4*)d_out);
    hipLaunchKernelGGL(rerank,      dim3(NN / 4),  dim3(256), 0, stream, x, keys, adj, ew);
}